// Round 12
// baseline (985.876 us; speedup 1.0000x reference)
//
#include <hip/hip_runtime.h>
#include <math.h>

#define NN 100000
#define NE 1600000
#define NG 1000
#define BN_EPS 1e-5f
#define AGG_BLOCKS 2048
#define NWAVES (AGG_BLOCKS * 4)
#define CAP 512      // per-wave LDS index cache (ints); cost-balance guarantees <512
#define ACC_MAX 30   // max nodes/wave (cost-balance guarantees <=25)
#define RNG 500
#define NBUK 200
#define KEYS (RNG * 4)   // (ldst, pass) keys per bucket
#define PASSW 25000      // src-window width: 25000 nodes * 128B = 3.2MB < 4MB L2
#define BB 512
#define BCAP 12288

typedef unsigned short ushort_t;
typedef unsigned int uint_t;
typedef __attribute__((ext_vector_type(8))) short bf16x8;
typedef __attribute__((ext_vector_type(4))) float f32x4;

__device__ inline float bf2f(ushort_t u) {
    return __uint_as_float(((uint_t)u) << 16);
}
__device__ inline ushort_t f2bf(float f) {
    uint_t u = __float_as_uint(f);
    u += 0x7FFFu + ((u >> 16) & 1u);   // RNE
    return (ushort_t)(u >> 16);
}

// ---------------- init ----------------

__global__ __launch_bounds__(256) void k_init(float* pooled, float* stats, int* bcnt) {
    int i = blockIdx.x * blockDim.x + threadIdx.x;
    int stride = gridDim.x * blockDim.x;
    for (int j = i; j < 5 * NG * 64; j += stride) pooled[j] = 0.f;
    for (int j = i; j < 1024; j += stride) stats[j] = 0.f;
    for (int j = i; j < NBUK; j += stride) bcnt[j] = 0;
}

__global__ __launch_bounds__(256) void k_f2bf(const float4* __restrict__ x, uint2* __restrict__ o) {
    int i = blockIdx.x * blockDim.x + threadIdx.x;
    int stride = gridDim.x * blockDim.x;
    for (int j = i; j < NN * 16; j += stride) {
        float4 v = x[j];
        uint2 r;
        r.x = (uint_t)f2bf(v.x) | ((uint_t)f2bf(v.y) << 16);
        r.y = (uint_t)f2bf(v.z) | ((uint_t)f2bf(v.w) << 16);
        o[j] = r;
    }
}

// ---------------- CSR build: block-local counting sort ----------------

__global__ __launch_bounds__(256) void k_cnt(const int* __restrict__ dst,
                                             int* __restrict__ cmat, int* __restrict__ bcnt) {
    __shared__ int l[NBUK];
    int b = blockIdx.x;
    for (int t = threadIdx.x; t < NBUK; t += 256) l[t] = 0;
    __syncthreads();
    int per = (NE + BB - 1) / BB;
    int s = b * per, e = min(NE, s + per);
    for (int i = s + threadIdx.x; i < e; i += 256) atomicAdd(&l[dst[i] / RNG], 1);
    __syncthreads();
    for (int t = threadIdx.x; t < NBUK; t += 256) {
        cmat[b * NBUK + t] = l[t];
        if (l[t]) atomicAdd(&bcnt[t], l[t]);
    }
}

__global__ __launch_bounds__(256) void k_boffscan(const int* __restrict__ bcnt,
                                                  const int* __restrict__ cmat,
                                                  int* __restrict__ wmat,
                                                  int* __restrict__ boff) {
    __shared__ int sb[256];
    __shared__ int s[256];
    int k = blockIdx.x;
    int t = threadIdx.x;
    int bv = (t < NBUK) ? bcnt[t] : 0;
    sb[t] = bv;
    __syncthreads();
    for (int o = 1; o < 256; o <<= 1) {
        int x = (t >= o) ? sb[t - o] : 0;
        __syncthreads();
        sb[t] += x;
        __syncthreads();
    }
    int boffk = sb[k] - ((k < NBUK) ? bcnt[k] : 0);
    if (t == 0) boff[k] = boffk;
    if (k == 0 && t == 0) boff[NBUK] = NE;
    int c0 = cmat[(2 * t) * NBUK + k];
    int c1 = cmat[(2 * t + 1) * NBUK + k];
    int sum = c0 + c1;
    s[t] = sum;
    __syncthreads();
    for (int o = 1; o < 256; o <<= 1) {
        int x = (t >= o) ? s[t - o] : 0;
        __syncthreads();
        s[t] += x;
        __syncthreads();
    }
    int excl = s[t] - sum + boffk;
    wmat[(2 * t) * NBUK + k] = excl;
    wmat[(2 * t + 1) * NBUK + k] = excl + c0;
}

__global__ __launch_bounds__(256) void k_bin2(const int* __restrict__ src, const int* __restrict__ dst,
                                              const int* __restrict__ wmat, uint_t* __restrict__ binned) {
    __shared__ int l[NBUK];
    int b = blockIdx.x;
    for (int t = threadIdx.x; t < NBUK; t += 256) l[t] = 0;
    __syncthreads();
    int per = (NE + BB - 1) / BB;
    int s = b * per, e = min(NE, s + per);
    for (int i = s + threadIdx.x; i < e; i += 256) {
        int d = dst[i];
        int k = d / RNG;
        int ldst = d - k * RNG;
        int r = atomicAdd(&l[k], 1);
        binned[wmat[b * NBUK + k] + r] = ((uint_t)ldst << 17) | (uint_t)src[i];
    }
}

// one block per bucket: counting sort by key=(ldst,src-pass) -> off[], poff4[], csr[]
__global__ __launch_bounds__(256) void k_bucket_finish(
    const uint_t* __restrict__ binned, const int* __restrict__ boff,
    int* __restrict__ off, int* __restrict__ poff4, int* __restrict__ csr)
{
    __shared__ uint_t ebuf[BCAP];
    __shared__ int cnt[KEYS];
    __shared__ int wpos[KEYS];
    __shared__ int tsum[256];
    int k = blockIdx.x;
    int t = threadIdx.x;
    int e0 = boff[k], e1 = boff[k + 1];
    int m = e1 - e0;
    bool inl = (m <= BCAP);

    for (int i = t; i < KEYS; i += 256) cnt[i] = 0;
    if (inl) for (int i = t; i < m; i += 256) ebuf[i] = binned[e0 + i];
    __syncthreads();
    for (int i = t; i < m; i += 256) {
        uint_t v = inl ? ebuf[i] : binned[e0 + i];
        int key = (int)(v >> 17) * 4 + (int)((v & 0x1FFFFu) / PASSW);
        atomicAdd(&cnt[key], 1);
    }
    __syncthreads();
    // scan of KEYS=2000: 8 keys/thread serial + block scan of thread sums
    int loc[8];
    int acc = 0;
#pragma unroll
    for (int e = 0; e < 8; e++) {
        int idx = t * 8 + e;
        int c = (idx < KEYS) ? cnt[idx] : 0;
        loc[e] = acc;
        acc += c;
    }
    tsum[t] = acc;
    __syncthreads();
    for (int o = 1; o < 256; o <<= 1) {
        int x = (t >= o) ? tsum[t - o] : 0;
        __syncthreads();
        tsum[t] += x;
        __syncthreads();
    }
    int texcl = tsum[t] - acc;
#pragma unroll
    for (int e = 0; e < 8; e++) {
        int idx = t * 8 + e;
        if (idx < KEYS) {
            int ex = texcl + loc[e];
            wpos[idx] = ex;
            poff4[(size_t)k * KEYS + idx] = e0 + ex;
            if ((idx & 3) == 0) off[k * RNG + (idx >> 2)] = e0 + ex;
        }
    }
    if (k == NBUK - 1 && t == 0) { off[NN] = NE; poff4[4 * NN] = NE; }
    __syncthreads();
    for (int i = t; i < m; i += 256) {
        uint_t v = inl ? ebuf[i] : binned[e0 + i];
        int key = (int)(v >> 17) * 4 + (int)((v & 0x1FFFFu) / PASSW);
        int r = atomicAdd(&wpos[key], 1);
        csr[e0 + r] = (int)(v & 0x1FFFFu);
    }
}

// cost-balanced wave start nodes: cost(n) = off[n] + 16*n bounds both edges and nodes per wave
__global__ __launch_bounds__(256) void k_wstart(const int* __restrict__ off, int* __restrict__ wstart) {
    int w = blockIdx.x * blockDim.x + threadIdx.x;
    if (w > NWAVES) return;
    if (w == NWAVES) { wstart[w] = NN; return; }
    long long t = ((long long)w * (NE + 16LL * NN)) / NWAVES;
    int lo = 0, hi = NN;
    while (lo < hi) {
        int mid = (lo + hi) >> 1;
        long long c = (long long)off[mid] + 16LL * mid;
        if (c < t) lo = mid + 1; else hi = mid;
    }
    wstart[w] = lo;
}

// ---------------- k_agg: 4-pass src-windowed gather + GEMM1 ----------------
// Pass p gathers only edges with src in [p*25000,(p+1)*25000): 3.2MB window is
// L2-resident per XCD. Cross-pass partials in per-wave LDS accf (f32).
// Epilogue: += affine(self), pool h_L, GEMM1 (lane = out feature), BN1 stats.

template<int DORELU>
__global__ __launch_bounds__(256) void k_agg(
    const ushort_t* __restrict__ zb,
    const float* __restrict__ stats2p, const float* __restrict__ g2p, const float* __restrict__ b2p,
    const int* __restrict__ csr, const int* __restrict__ off, const int* __restrict__ poff4,
    const int* __restrict__ wstart,
    const float* __restrict__ W1, ushort_t* __restrict__ yb,
    float* __restrict__ stats1,
    const int* __restrict__ gid, float* __restrict__ poolL)
{
    __shared__ __align__(16) float accf[4][ACC_MAX][64];
    __shared__ int sidx[4][CAP];
    __shared__ int spo[4][4 * ACC_MAX + 4];
    __shared__ float sred[128];
    int lane = threadIdx.x & 63;
    int wslot = threadIdx.x >> 6;
    int wid = blockIdx.x * 4 + wslot;
    int fl = lane & 15;
    int grp = lane >> 4;

    float scv0 = 1.f, scv1 = 1.f, scv2 = 1.f, scv3 = 1.f;
    float shv0 = 0.f, shv1 = 0.f, shv2 = 0.f, shv3 = 0.f;
    if (DORELU) {
        int f = 4 * fl;
#define MKCO(q, scq, shq) { \
        float mean = stats2p[f + q] * (1.f / NN); \
        float var  = stats2p[64 + f + q] * (1.f / NN) - mean * mean; \
        scq = rsqrtf(var + BN_EPS) * g2p[f + q]; \
        shq = b2p[f + q] - mean * scq; }
        MKCO(0, scv0, shv0) MKCO(1, scv1, shv1) MKCO(2, scv2, shv2) MKCO(3, scv3, shv3)
#undef MKCO
    }

    float Wc[64];
#pragma unroll
    for (int k = 0; k < 64; k++) Wc[k] = W1[k * 64 + lane];

    float ls = 0.f, lss = 0.f;

    int n0 = wstart[wid], n1 = wstart[wid + 1];
    int nn = n1 - n0;

    if (nn > 0) {
        int e0 = off[n0];
        int eEnd = off[n1];
        int tot = eEnd - e0;
        int lim = min(tot, CAP);
        for (int t = lane; t < lim; t += 64) sidx[wslot][t] = csr[e0 + t];
        for (int t = lane; t <= 4 * nn; t += 64) spo[wslot][t] = poff4[4 * n0 + t];
        float* af = &accf[wslot][0][0];
        for (int t = lane; t < nn * 64; t += 64) af[t] = 0.f;

#define AFF(t, scq, shq) (DORELU ? fmaxf(fmaf(t, scq, shq), 0.f) : (t))
#define UNPK(p, t0, t1, t2, t3) \
        float t0 = AFF(__uint_as_float(p.x << 16), scv0, shv0); \
        float t1 = AFF(__uint_as_float(p.x & 0xFFFF0000u), scv1, shv1); \
        float t2 = AFF(__uint_as_float(p.y << 16), scv2, shv2); \
        float t3 = AFF(__uint_as_float(p.y & 0xFFFF0000u), scv3, shv3);

        // ---- 4 src-windowed passes ----
        for (int p = 0; p < 4; ++p) {
            for (int m = 0; m < nn; ++m) {
                int j0 = spo[wslot][4 * m + p] - e0;
                int j1 = spo[wslot][4 * m + p + 1] - e0;
                if (j0 >= j1) continue;      // uniform per wave
                float b0 = 0.f, b1 = 0.f, b2 = 0.f, b3 = 0.f;
                int j = j0 + grp;
                if (j1 <= lim) {
                    for (; j < j1; j += 4) {
                        int i0 = sidx[wslot][j];
                        uint2 q0 = *(const uint2*)(zb + ((size_t)i0 << 6) + (fl << 2));
                        UNPK(q0, t0, t1, t2, t3) b0 += t0; b1 += t1; b2 += t2; b3 += t3;
                    }
                } else {
                    for (; j < j1; j += 4) {
                        int i0 = csr[e0 + j];
                        uint2 q0 = *(const uint2*)(zb + ((size_t)i0 << 6) + (fl << 2));
                        UNPK(q0, t0, t1, t2, t3) b0 += t0; b1 += t1; b2 += t2; b3 += t3;
                    }
                }
                b0 += __shfl_xor(b0, 16); b0 += __shfl_xor(b0, 32);
                b1 += __shfl_xor(b1, 16); b1 += __shfl_xor(b1, 32);
                b2 += __shfl_xor(b2, 16); b2 += __shfl_xor(b2, 32);
                b3 += __shfl_xor(b3, 16); b3 += __shfl_xor(b3, 32);
                if (grp == 0) {
                    float4* ap = (float4*)accf[wslot][m];
                    float4 c = ap[fl];
                    c.x += b0; c.y += b1; c.z += b2; c.w += b3;
                    ap[fl] = c;
                }
            }
        }

        // ---- epilogue: self + pool + GEMM1 + stats ----
        int curg = -1;
        float p0 = 0.f, p1 = 0.f, p2 = 0.f, p3 = 0.f;
        for (int m = 0; m < nn; ++m) {
            int n = n0 + m;
            uint2 sp = *(const uint2*)(zb + ((size_t)n << 6) + (fl << 2));
            UNPK(sp, s0v, s1v, s2v, s3v)

            int g = gid[n];
            if (g != curg) {
                if (curg >= 0 && grp == 0) {
                    atomicAdd(&poolL[curg * 64 + 4 * fl], p0);
                    atomicAdd(&poolL[curg * 64 + 4 * fl + 1], p1);
                    atomicAdd(&poolL[curg * 64 + 4 * fl + 2], p2);
                    atomicAdd(&poolL[curg * 64 + 4 * fl + 3], p3);
                }
                curg = g; p0 = p1 = p2 = p3 = 0.f;
            }
            p0 += s0v; p1 += s1v; p2 += s2v; p3 += s3v;

            if (grp == 0) {
                float4* ap = (float4*)accf[wslot][m];
                float4 c = ap[fl];
                c.x += s0v; c.y += s1v; c.z += s2v; c.w += s3v;
                ap[fl] = c;
            }
            float yl = 0.f;
#pragma unroll
            for (int k = 0; k < 16; k++) {
                float4 z4 = *(const float4*)&accf[wslot][m][k * 4];
                yl = fmaf(z4.x, Wc[4 * k], yl);
                yl = fmaf(z4.y, Wc[4 * k + 1], yl);
                yl = fmaf(z4.z, Wc[4 * k + 2], yl);
                yl = fmaf(z4.w, Wc[4 * k + 3], yl);
            }
            yb[(size_t)n * 64 + lane] = f2bf(yl);
            ls += yl;
            lss += yl * yl;
        }
        if (curg >= 0 && grp == 0) {
            atomicAdd(&poolL[curg * 64 + 4 * fl], p0);
            atomicAdd(&poolL[curg * 64 + 4 * fl + 1], p1);
            atomicAdd(&poolL[curg * 64 + 4 * fl + 2], p2);
            atomicAdd(&poolL[curg * 64 + 4 * fl + 3], p3);
        }
#undef AFF
#undef UNPK
    }

    if (threadIdx.x < 128) sred[threadIdx.x] = 0.f;
    __syncthreads();
    atomicAdd(&sred[lane], ls);
    atomicAdd(&sred[64 + lane], lss);
    __syncthreads();
    if (threadIdx.x < 128) atomicAdd(&stats1[threadIdx.x], sred[threadIdx.x]);
}

// ---------------- k_g2m: MFMA BN1+ReLU+GEMM2+BN2stats (unchanged) ----------------

__global__ __launch_bounds__(256) void k_g2m(
    const ushort_t* __restrict__ yb, const float* __restrict__ stats1,
    const float* __restrict__ g1, const float* __restrict__ b1,
    const float* __restrict__ W2, ushort_t* __restrict__ zb,
    float* __restrict__ stats2)
{
    __shared__ ushort_t zt[4][16][64];
    __shared__ float sred[128];
    int lane = threadIdx.x & 63;
    int wslot = threadIdx.x >> 6;
    int w = blockIdx.x * 4 + wslot;
    int r = lane & 15;
    int g = lane >> 4;

    if (threadIdx.x < 128) sred[threadIdx.x] = 0.f;
    __syncthreads();

    if (w < NN / 16) {
        int n0 = w * 16;

        float scL[8], shL[8], scH[8], shH[8];
#pragma unroll
        for (int e = 0; e < 8; e++) {
            int f = g * 8 + e;
            float mean = stats1[f] * (1.f / NN);
            float var  = stats1[64 + f] * (1.f / NN) - mean * mean;
            scL[e] = rsqrtf(var + BN_EPS) * g1[f];
            shL[e] = b1[f] - mean * scL[e];
            int f2 = 32 + f;
            float mean2 = stats1[f2] * (1.f / NN);
            float var2  = stats1[64 + f2] * (1.f / NN) - mean2 * mean2;
            scH[e] = rsqrtf(var2 + BN_EPS) * g1[f2];
            shH[e] = b1[f2] - mean2 * scH[e];
        }

        bf16x8 B00, B01, B02, B03, B10, B11, B12, B13;
#pragma unroll
        for (int j = 0; j < 8; j++) {
            int k0 = (g * 8 + j) * 64;
            int k1 = (32 + g * 8 + j) * 64;
            B00[j] = (short)f2bf(W2[k0 + r]);
            B01[j] = (short)f2bf(W2[k0 + 16 + r]);
            B02[j] = (short)f2bf(W2[k0 + 32 + r]);
            B03[j] = (short)f2bf(W2[k0 + 48 + r]);
            B10[j] = (short)f2bf(W2[k1 + r]);
            B11[j] = (short)f2bf(W2[k1 + 16 + r]);
            B12[j] = (short)f2bf(W2[k1 + 32 + r]);
            B13[j] = (short)f2bf(W2[k1 + 48 + r]);
        }

        union { uint4 u; ushort_t s[8]; } a0u, a1u;
        a0u.u = *(const uint4*)(yb + (size_t)(n0 + r) * 64 + g * 8);
        a1u.u = *(const uint4*)(yb + (size_t)(n0 + r) * 64 + 32 + g * 8);
        bf16x8 A0, A1;
#pragma unroll
        for (int e = 0; e < 8; e++) {
            float v0 = fmaxf(fmaf(bf2f(a0u.s[e]), scL[e], shL[e]), 0.f);
            float v1 = fmaxf(fmaf(bf2f(a1u.s[e]), scH[e], shH[e]), 0.f);
            A0[e] = (short)f2bf(v0);
            A1[e] = (short)f2bf(v1);
        }

        f32x4 acc0 = {0.f, 0.f, 0.f, 0.f};
        f32x4 acc1 = acc0, acc2 = acc0, acc3 = acc0;
        acc0 = __builtin_amdgcn_mfma_f32_16x16x32_bf16(A0, B00, acc0, 0, 0, 0);
        acc1 = __builtin_amdgcn_mfma_f32_16x16x32_bf16(A0, B01, acc1, 0, 0, 0);
        acc2 = __builtin_amdgcn_mfma_f32_16x16x32_bf16(A0, B02, acc2, 0, 0, 0);
        acc3 = __builtin_amdgcn_mfma_f32_16x16x32_bf16(A0, B03, acc3, 0, 0, 0);
        acc0 = __builtin_amdgcn_mfma_f32_16x16x32_bf16(A1, B10, acc0, 0, 0, 0);
        acc1 = __builtin_amdgcn_mfma_f32_16x16x32_bf16(A1, B11, acc1, 0, 0, 0);
        acc2 = __builtin_amdgcn_mfma_f32_16x16x32_bf16(A1, B12, acc2, 0, 0, 0);
        acc3 = __builtin_amdgcn_mfma_f32_16x16x32_bf16(A1, B13, acc3, 0, 0, 0);

        float ls0 = acc0.x + acc0.y + acc0.z + acc0.w;
        float ls1 = acc1.x + acc1.y + acc1.z + acc1.w;
        float ls2 = acc2.x + acc2.y + acc2.z + acc2.w;
        float ls3 = acc3.x + acc3.y + acc3.z + acc3.w;
        float lq0 = acc0.x * acc0.x + acc0.y * acc0.y + acc0.z * acc0.z + acc0.w * acc0.w;
        float lq1 = acc1.x * acc1.x + acc1.y * acc1.y + acc1.z * acc1.z + acc1.w * acc1.w;
        float lq2 = acc2.x * acc2.x + acc2.y * acc2.y + acc2.z * acc2.z + acc2.w * acc2.w;
        float lq3 = acc3.x * acc3.x + acc3.y * acc3.y + acc3.z * acc3.z + acc3.w * acc3.w;
        ls0 += __shfl_xor(ls0, 16); ls0 += __shfl_xor(ls0, 32);
        ls1 += __shfl_xor(ls1, 16); ls1 += __shfl_xor(ls1, 32);
        ls2 += __shfl_xor(ls2, 16); ls2 += __shfl_xor(ls2, 32);
        ls3 += __shfl_xor(ls3, 16); ls3 += __shfl_xor(ls3, 32);
        lq0 += __shfl_xor(lq0, 16); lq0 += __shfl_xor(lq0, 32);
        lq1 += __shfl_xor(lq1, 16); lq1 += __shfl_xor(lq1, 32);
        lq2 += __shfl_xor(lq2, 16); lq2 += __shfl_xor(lq2, 32);
        lq3 += __shfl_xor(lq3, 16); lq3 += __shfl_xor(lq3, 32);
        if (lane < 16) {
            atomicAdd(&sred[lane], ls0);
            atomicAdd(&sred[16 + lane], ls1);
            atomicAdd(&sred[32 + lane], ls2);
            atomicAdd(&sred[48 + lane], ls3);
            atomicAdd(&sred[64 + lane], lq0);
            atomicAdd(&sred[80 + lane], lq1);
            atomicAdd(&sred[96 + lane], lq2);
            atomicAdd(&sred[112 + lane], lq3);
        }

        zt[wslot][g * 4 + 0][r]      = f2bf(acc0.x);
        zt[wslot][g * 4 + 1][r]      = f2bf(acc0.y);
        zt[wslot][g * 4 + 2][r]      = f2bf(acc0.z);
        zt[wslot][g * 4 + 3][r]      = f2bf(acc0.w);
        zt[wslot][g * 4 + 0][16 + r] = f2bf(acc1.x);
        zt[wslot][g * 4 + 1][16 + r] = f2bf(acc1.y);
        zt[wslot][g * 4 + 2][16 + r] = f2bf(acc1.z);
        zt[wslot][g * 4 + 3][16 + r] = f2bf(acc1.w);
        zt[wslot][g * 4 + 0][32 + r] = f2bf(acc2.x);
        zt[wslot][g * 4 + 1][32 + r] = f2bf(acc2.y);
        zt[wslot][g * 4 + 2][32 + r] = f2bf(acc2.z);
        zt[wslot][g * 4 + 3][32 + r] = f2bf(acc2.w);
        zt[wslot][g * 4 + 0][48 + r] = f2bf(acc3.x);
        zt[wslot][g * 4 + 1][48 + r] = f2bf(acc3.y);
        zt[wslot][g * 4 + 2][48 + r] = f2bf(acc3.z);
        zt[wslot][g * 4 + 3][48 + r] = f2bf(acc3.w);

        int nl = lane >> 2;
        int c0 = (lane & 3) * 16;
        uint4 q0 = *(const uint4*)&zt[wslot][nl][c0];
        uint4 q1 = *(const uint4*)&zt[wslot][nl][c0 + 8];
        *(uint4*)(zb + (size_t)(n0 + nl) * 64 + c0) = q0;
        *(uint4*)(zb + (size_t)(n0 + nl) * 64 + c0 + 8) = q1;
    }

    __syncthreads();
    if (threadIdx.x < 128) atomicAdd(&stats2[threadIdx.x], sred[threadIdx.x]);
}

// ---------------- final hidden rep pooling (h_4) ----------------

__global__ __launch_bounds__(256) void k_pool4(
    const ushort_t* __restrict__ zb,
    const float* __restrict__ stats2, const float* __restrict__ g2, const float* __restrict__ b2,
    const int* __restrict__ gid, float* __restrict__ pool)
{
    int lane = threadIdx.x & 63;
    int wslot = threadIdx.x >> 6;
    int wid = blockIdx.x * 4 + wslot;
    int nw = gridDim.x * 4;
    int chunk = (NN + nw - 1) / nw;
    int n0 = wid * chunk, n1 = min(NN, n0 + chunk);
    if (n0 >= n1) return;

    float mean = stats2[lane] * (1.f / NN);
    float var  = stats2[64 + lane] * (1.f / NN) - mean * mean;
    float sc = rsqrtf(var + BN_EPS) * g2[lane];
    float sh = b2[lane] - mean * sc;

    int curg = -1;
    float pacc = 0.f;
    for (int n = n0; n < n1; ++n) {
        float v = fmaxf(fmaf(bf2f(zb[(size_t)n * 64 + lane]), sc, sh), 0.f);
        int g = gid[n];
        if (g != curg) {
            if (curg >= 0) atomicAdd(&pool[curg * 64 + lane], pacc);
            curg = g; pacc = 0.f;
        }
        pacc += v;
    }
    if (curg >= 0) atomicAdd(&pool[curg * 64 + lane], pacc);
}

// ---------------- epilogue ----------------

__global__ __launch_bounds__(256) void k_final(
    const float* __restrict__ pooled, const float* __restrict__ pW,
    const float* __restrict__ pb, float* __restrict__ out)
{
    int t = blockIdx.x * blockDim.x + threadIdx.x;
    int g = t >> 4;
    int c = t & 15;
    if (g >= NG) return;
    float acc = 0.f;
#pragma unroll
    for (int i = 0; i < 5; i++) {
        const float* P = pooled + (size_t)i * NG * 64 + g * 64;
        const float* W = pW + i * 64 * 16;
        float a = 0.f;
#pragma unroll
        for (int k = 0; k < 64; k++) a += P[k] * W[k * 16 + c];
        acc += a + pb[i * 16 + c];
    }
    float m = acc;
    for (int o = 1; o < 16; o <<= 1) m = fmaxf(m, __shfl_xor(m, o, 16));
    float e = expf(acc - m);
    float s = e;
    for (int o = 1; o < 16; o <<= 1) s += __shfl_xor(s, o, 16);
    out[g * 16 + c] = acc - m - logf(s);
}

// ---------------- launch ----------------

extern "C" void kernel_launch(void* const* d_in, const int* in_sizes, int n_in,
                              void* d_out, int out_size, void* d_ws, size_t ws_size,
                              hipStream_t stream) {
    const float* feat = (const float*)d_in[0];
    const float* W1   = (const float*)d_in[1];
    const float* W2   = (const float*)d_in[2];
    const float* bn1g = (const float*)d_in[3];
    const float* bn1b = (const float*)d_in[4];
    const float* bn2g = (const float*)d_in[5];
    const float* bn2b = (const float*)d_in[6];
    const float* pW   = (const float*)d_in[7];
    const float* pb   = (const float*)d_in[8];
    const int* src = (const int*)d_in[9];
    const int* dst = (const int*)d_in[10];
    const int* gid = (const int*)d_in[11];
    float* out = (float*)d_out;

    char* ws = (char*)d_ws;
    size_t o = 0;
    auto alloc = [&](size_t bytes) {
        void* p = ws + o;
        o += (bytes + 255) & ~(size_t)255;
        return p;
    };
    ushort_t* zb  = (ushort_t*)alloc((size_t)NN * 64 * 2);
    ushort_t* yb  = (ushort_t*)alloc((size_t)NN * 64 * 2);
    float* pooled = (float*)alloc((size_t)5 * NG * 64 * 4);
    float* stats  = (float*)alloc(1024 * 4);
    int* off   = (int*)alloc((size_t)(NN + 1) * 4);
    int* poff4 = (int*)alloc((size_t)(4 * NN + 4) * 4);
    int* csr   = (int*)alloc((size_t)NE * 4);
    uint_t* binned = (uint_t*)alloc((size_t)NE * 4);
    int* cmat = (int*)alloc((size_t)BB * NBUK * 4);
    int* wmat = (int*)alloc((size_t)BB * NBUK * 4);
    int* bcnt = (int*)alloc(NBUK * 4);
    int* boff = (int*)alloc((NBUK + 1) * 4);
    int* wstart = (int*)alloc((NWAVES + 1) * 4);

    k_init<<<256, 256, 0, stream>>>(pooled, stats, bcnt);
    k_f2bf<<<1024, 256, 0, stream>>>((const float4*)feat, (uint2*)zb);
    k_cnt<<<BB, 256, 0, stream>>>(dst, cmat, bcnt);
    k_boffscan<<<NBUK, 256, 0, stream>>>(bcnt, cmat, wmat, boff);
    k_bin2<<<BB, 256, 0, stream>>>(src, dst, wmat, binned);
    k_bucket_finish<<<NBUK, 256, 0, stream>>>(binned, boff, off, poff4, csr);
    k_wstart<<<(NWAVES + 1 + 255) / 256, 256, 0, stream>>>(off, wstart);

    int g2m_blocks = (NN / 16 + 3) / 4;   // 1563
    for (int L = 0; L < 4; ++L) {
        float* s1 = stats + L * 256;
        float* s2 = s1 + 128;
        if (L == 0) {
            k_agg<0><<<AGG_BLOCKS, 256, 0, stream>>>(zb, nullptr, nullptr, nullptr,
                                                     csr, off, poff4, wstart, W1 + L * 4096, yb, s1,
                                                     gid, pooled + (size_t)L * NG * 64);
        } else {
            k_agg<1><<<AGG_BLOCKS, 256, 0, stream>>>(zb, stats + (L - 1) * 256 + 128,
                                                     bn2g + (L - 1) * 64, bn2b + (L - 1) * 64,
                                                     csr, off, poff4, wstart, W1 + L * 4096, yb, s1,
                                                     gid, pooled + (size_t)L * NG * 64);
        }
        k_g2m<<<g2m_blocks, 256, 0, stream>>>(yb, s1, bn1g + L * 64, bn1b + L * 64,
                                              W2 + L * 4096, zb, s2);
    }
    k_pool4<<<AGG_BLOCKS, 256, 0, stream>>>(zb, stats + 3 * 256 + 128, bn2g + 3 * 64, bn2b + 3 * 64,
                                            gid, pooled + (size_t)4 * NG * 64);
    k_final<<<(NG * 16 + 255) / 256, 256, 0, stream>>>(pooled, pW, pb, out);
}

// Round 13
// 665.122 us; speedup vs baseline: 1.4822x; 1.4822x over previous
//
#include <hip/hip_runtime.h>
#include <math.h>

#define NN 100000
#define NE 1600000
#define NG 1000
#define BN_EPS 1e-5f
#define AGG_BLOCKS 2048
#define NWAVES (AGG_BLOCKS * 4)
#define CAP 576      // per-wave LDS index cache; cost-balance bounds wave edges <= ~461
#define MMAX 48      // max nodes/wave; cost-balance bounds <= ~29
#define RNG 500
#define NBUK 200
#define BB 512
#define BCAP 12288

typedef unsigned short ushort_t;
typedef unsigned int uint_t;
typedef __attribute__((ext_vector_type(8))) short bf16x8;
typedef __attribute__((ext_vector_type(4))) float f32x4;

__device__ inline float bf2f(ushort_t u) {
    return __uint_as_float(((uint_t)u) << 16);
}
__device__ inline ushort_t f2bf(float f) {
    uint_t u = __float_as_uint(f);
    u += 0x7FFFu + ((u >> 16) & 1u);   // RNE
    return (ushort_t)(u >> 16);
}

// ---------------- init ----------------

__global__ __launch_bounds__(256) void k_init(float* pooled, float* stats, int* bcnt) {
    int i = blockIdx.x * blockDim.x + threadIdx.x;
    int stride = gridDim.x * blockDim.x;
    for (int j = i; j < 5 * NG * 64; j += stride) pooled[j] = 0.f;
    for (int j = i; j < 1024; j += stride) stats[j] = 0.f;
    for (int j = i; j < NBUK; j += stride) bcnt[j] = 0;
}

__global__ __launch_bounds__(256) void k_f2bf(const float4* __restrict__ x, uint2* __restrict__ o) {
    int i = blockIdx.x * blockDim.x + threadIdx.x;
    int stride = gridDim.x * blockDim.x;
    for (int j = i; j < NN * 16; j += stride) {
        float4 v = x[j];
        uint2 r;
        r.x = (uint_t)f2bf(v.x) | ((uint_t)f2bf(v.y) << 16);
        r.y = (uint_t)f2bf(v.z) | ((uint_t)f2bf(v.w) << 16);
        o[j] = r;
    }
}

// ---------------- CSR build: block-local counting sort (unchanged from R11) ----------------

__global__ __launch_bounds__(256) void k_cnt(const int* __restrict__ dst,
                                             int* __restrict__ cmat, int* __restrict__ bcnt) {
    __shared__ int l[NBUK];
    int b = blockIdx.x;
    for (int t = threadIdx.x; t < NBUK; t += 256) l[t] = 0;
    __syncthreads();
    int per = (NE + BB - 1) / BB;
    int s = b * per, e = min(NE, s + per);
    for (int i = s + threadIdx.x; i < e; i += 256) atomicAdd(&l[dst[i] / RNG], 1);
    __syncthreads();
    for (int t = threadIdx.x; t < NBUK; t += 256) {
        cmat[b * NBUK + t] = l[t];
        if (l[t]) atomicAdd(&bcnt[t], l[t]);
    }
}

__global__ __launch_bounds__(256) void k_boffscan(const int* __restrict__ bcnt,
                                                  const int* __restrict__ cmat,
                                                  int* __restrict__ wmat,
                                                  int* __restrict__ boff) {
    __shared__ int sb[256];
    __shared__ int s[256];
    int k = blockIdx.x;
    int t = threadIdx.x;
    int bv = (t < NBUK) ? bcnt[t] : 0;
    sb[t] = bv;
    __syncthreads();
    for (int o = 1; o < 256; o <<= 1) {
        int x = (t >= o) ? sb[t - o] : 0;
        __syncthreads();
        sb[t] += x;
        __syncthreads();
    }
    int boffk = sb[k] - ((k < NBUK) ? bcnt[k] : 0);
    if (t == 0) boff[k] = boffk;
    if (k == 0 && t == 0) boff[NBUK] = NE;
    int c0 = cmat[(2 * t) * NBUK + k];
    int c1 = cmat[(2 * t + 1) * NBUK + k];
    int sum = c0 + c1;
    s[t] = sum;
    __syncthreads();
    for (int o = 1; o < 256; o <<= 1) {
        int x = (t >= o) ? s[t - o] : 0;
        __syncthreads();
        s[t] += x;
        __syncthreads();
    }
    int excl = s[t] - sum + boffk;
    wmat[(2 * t) * NBUK + k] = excl;
    wmat[(2 * t + 1) * NBUK + k] = excl + c0;
}

__global__ __launch_bounds__(256) void k_bin2(const int* __restrict__ src, const int* __restrict__ dst,
                                              const int* __restrict__ wmat, uint_t* __restrict__ binned) {
    __shared__ int l[NBUK];
    int b = blockIdx.x;
    for (int t = threadIdx.x; t < NBUK; t += 256) l[t] = 0;
    __syncthreads();
    int per = (NE + BB - 1) / BB;
    int s = b * per, e = min(NE, s + per);
    for (int i = s + threadIdx.x; i < e; i += 256) {
        int d = dst[i];
        int k = d / RNG;
        int ldst = d - k * RNG;
        int r = atomicAdd(&l[k], 1);
        binned[wmat[b * NBUK + k] + r] = ((uint_t)ldst << 17) | (uint_t)src[i];
    }
}

__global__ __launch_bounds__(256) void k_bucket_finish(
    const uint_t* __restrict__ binned, const int* __restrict__ boff,
    int* __restrict__ off, int* __restrict__ csr)
{
    __shared__ uint_t ebuf[BCAP];
    __shared__ int cnt[512];
    __shared__ int a[256];
    __shared__ int wpos[RNG];
    int k = blockIdx.x;
    int t = threadIdx.x;
    int e0 = boff[k], e1 = boff[k + 1];
    int m = e1 - e0;
    bool inl = (m <= BCAP);

    cnt[t] = 0; cnt[t + 256] = 0;
    if (inl) for (int i = t; i < m; i += 256) ebuf[i] = binned[e0 + i];
    __syncthreads();
    for (int i = t; i < m; i += 256) {
        uint_t v = inl ? ebuf[i] : binned[e0 + i];
        atomicAdd(&cnt[v >> 17], 1);
    }
    __syncthreads();
    int c0 = cnt[2 * t], c1 = cnt[2 * t + 1];
    int sum = c0 + c1;
    a[t] = sum;
    __syncthreads();
    for (int o = 1; o < 256; o <<= 1) {
        int x = (t >= o) ? a[t - o] : 0;
        __syncthreads();
        a[t] += x;
        __syncthreads();
    }
    int excl = a[t] - sum;
    int base = k * RNG;
    if (2 * t < RNG) { off[base + 2 * t] = e0 + excl; wpos[2 * t] = excl; }
    if (2 * t + 1 < RNG) { off[base + 2 * t + 1] = e0 + excl + c0; wpos[2 * t + 1] = excl + c0; }
    if (k == NBUK - 1 && t == 0) off[NN] = NE;
    __syncthreads();
    for (int i = t; i < m; i += 256) {
        uint_t v = inl ? ebuf[i] : binned[e0 + i];
        int ldst = (int)(v >> 17);
        int r = atomicAdd(&wpos[ldst], 1);
        csr[e0 + r] = (int)(v & 0x1FFFFu);
    }
}

// cost-balanced wave starts: cost(n) = off[n] + 16*n bounds edges AND nodes per wave
__global__ __launch_bounds__(256) void k_wstart(const int* __restrict__ off, int* __restrict__ wstart) {
    int w = blockIdx.x * blockDim.x + threadIdx.x;
    if (w > NWAVES) return;
    if (w == NWAVES) { wstart[w] = NN; return; }
    long long t = ((long long)w * (NE + 16LL * NN)) / NWAVES;
    int lo = 0, hi = NN;
    while (lo < hi) {
        int mid = (lo + hi) >> 1;
        long long c = (long long)off[mid] + 16LL * mid;
        if (c < t) lo = mid + 1; else hi = mid;
    }
    wstart[w] = lo;
}

// ---------------- k_agg: quartet-pipelined gather (depth 4) + GEMM1 ----------------
// Edge stream consumed as 4-edge quartets via 4 rotating register slots:
// consume quartet q while q+1..q+4 loads are in flight (16 lines/wave).
// Node boundaries via per-lane predication against wave-uniform soff[] in LDS;
// FLUSH (shfl-combine + self + pool + GEMM1 + stats) inlined at boundaries.

template<int DORELU>
__global__ __launch_bounds__(256) void k_agg(
    const ushort_t* __restrict__ zb,
    const float* __restrict__ stats2p, const float* __restrict__ g2p, const float* __restrict__ b2p,
    const int* __restrict__ csr, const int* __restrict__ off, const int* __restrict__ wstart,
    const float* __restrict__ W1, ushort_t* __restrict__ yb,
    float* __restrict__ stats1,
    const int* __restrict__ gid, float* __restrict__ poolL)
{
    __shared__ __align__(16) float buf[4][64];
    __shared__ int sidx[4][CAP];
    __shared__ int soff[4][MMAX + 1];
    __shared__ int sgid[4][MMAX];
    __shared__ float sred[128];
    int lane = threadIdx.x & 63;
    int wslot = threadIdx.x >> 6;
    int wid = blockIdx.x * 4 + wslot;
    int fl = lane & 15;
    int grp = lane >> 4;

    float scv0 = 1.f, scv1 = 1.f, scv2 = 1.f, scv3 = 1.f;
    float shv0 = 0.f, shv1 = 0.f, shv2 = 0.f, shv3 = 0.f;
    if (DORELU) {
        int f = 4 * fl;
#define MKCO(q, scq, shq) { \
        float mean = stats2p[f + q] * (1.f / NN); \
        float var  = stats2p[64 + f + q] * (1.f / NN) - mean * mean; \
        scq = rsqrtf(var + BN_EPS) * g2p[f + q]; \
        shq = b2p[f + q] - mean * scq; }
        MKCO(0, scv0, shv0) MKCO(1, scv1, shv1) MKCO(2, scv2, shv2) MKCO(3, scv3, shv3)
#undef MKCO
    }

    float Wc[64];
#pragma unroll
    for (int k = 0; k < 64; k++) Wc[k] = W1[k * 64 + lane];

    float ls = 0.f, lss = 0.f;

    int n0 = wstart[wid], n1 = wstart[wid + 1];
    int nn = n1 - n0;

    if (nn > 0) {
        int e0 = off[n0];
        int tot = off[n1] - e0;            // <= CAP by cost balance
        for (int t = lane; t < tot; t += 64) sidx[wslot][t] = csr[e0 + t];
        for (int t = lane; t <= nn; t += 64) soff[wslot][t] = off[n0 + t] - e0;
        for (int t = lane; t < nn; t += 64) sgid[wslot][t] = gid[n0 + t];

        int m = 0;
        float b0 = 0.f, b1 = 0.f, b2 = 0.f, b3 = 0.f;
        int curg = -1;
        float p0 = 0.f, p1 = 0.f, p2 = 0.f, p3 = 0.f;

#define AFF(t, scq, shq) (DORELU ? fmaxf(fmaf(t, scq, shq), 0.f) : (t))
#define UNPK(p, t0, t1, t2, t3) \
        float t0 = AFF(__uint_as_float(p.x << 16), scv0, shv0); \
        float t1 = AFF(__uint_as_float(p.x & 0xFFFF0000u), scv1, shv1); \
        float t2 = AFF(__uint_as_float(p.y << 16), scv2, shv2); \
        float t3 = AFF(__uint_as_float(p.y & 0xFFFF0000u), scv3, shv3);

#define LDQ(dstv, qq) { \
        int _i = 4 * (qq) + grp; \
        int _r = (_i < tot) ? sidx[wslot][_i] : 0; \
        dstv = *(const uint2*)(zb + ((size_t)_r << 6) + (fl << 2)); }

#define FLUSH() { \
        b0 += __shfl_xor(b0, 16); b0 += __shfl_xor(b0, 32); \
        b1 += __shfl_xor(b1, 16); b1 += __shfl_xor(b1, 32); \
        b2 += __shfl_xor(b2, 16); b2 += __shfl_xor(b2, 32); \
        b3 += __shfl_xor(b3, 16); b3 += __shfl_xor(b3, 32); \
        UNPK(S, s0v, s1v, s2v, s3v) \
        if (m + 1 < nn) { S = *(const uint2*)(zb + ((size_t)(n0 + m + 1) << 6) + (fl << 2)); } \
        int gloc = sgid[wslot][m]; \
        if (gloc != curg) { \
            if (curg >= 0 && grp == 0) { \
                atomicAdd(&poolL[curg * 64 + 4 * fl], p0); \
                atomicAdd(&poolL[curg * 64 + 4 * fl + 1], p1); \
                atomicAdd(&poolL[curg * 64 + 4 * fl + 2], p2); \
                atomicAdd(&poolL[curg * 64 + 4 * fl + 3], p3); \
            } \
            curg = gloc; p0 = p1 = p2 = p3 = 0.f; \
        } \
        p0 += s0v; p1 += s1v; p2 += s2v; p3 += s3v; \
        if (grp == 0) { \
            ((float4*)buf[wslot])[fl] = make_float4(s0v + b0, s1v + b1, s2v + b2, s3v + b3); \
        } \
        float yl = 0.f; \
        _Pragma("unroll") \
        for (int k = 0; k < 16; k++) { \
            float4 z4 = *(const float4*)&buf[wslot][k * 4]; \
            yl = fmaf(z4.x, Wc[4 * k], yl); \
            yl = fmaf(z4.y, Wc[4 * k + 1], yl); \
            yl = fmaf(z4.z, Wc[4 * k + 2], yl); \
            yl = fmaf(z4.w, Wc[4 * k + 3], yl); \
        } \
        yb[(size_t)(n0 + m) * 64 + lane] = f2bf(yl); \
        ls += yl; lss += yl * yl; \
        b0 = b1 = b2 = b3 = 0.f; }

#define CONSUME(PV, qq) { \
        int myp = 4 * (qq) + grp; \
        UNPK(PV, t0, t1, t2, t3) \
        if (m < nn) { \
            if (myp < soff[wslot][m + 1]) { b0 += t0; b1 += t1; b2 += t2; b3 += t3; } \
            while (m < nn && soff[wslot][m + 1] <= 4 * (qq) + 3) { \
                FLUSH(); \
                m++; \
                if (m < nn && myp >= soff[wslot][m] && myp < soff[wslot][m + 1]) { \
                    b0 += t0; b1 += t1; b2 += t2; b3 += t3; \
                } \
            } \
        } }

        int Q = (tot + 3) >> 2;
        uint2 P0, P1, P2, P3;
        LDQ(P0, 0) LDQ(P1, 1) LDQ(P2, 2) LDQ(P3, 3)
        uint2 S = *(const uint2*)(zb + ((size_t)n0 << 6) + (fl << 2));

        for (int q4 = 0; q4 < Q; q4 += 4) {
            { CONSUME(P0, q4 + 0) } LDQ(P0, q4 + 4)
            { CONSUME(P1, q4 + 1) } LDQ(P1, q4 + 5)
            { CONSUME(P2, q4 + 2) } LDQ(P2, q4 + 6)
            { CONSUME(P3, q4 + 3) } LDQ(P3, q4 + 7)
        }
        // tail: flush remaining (covers Q==0 / empty trailing nodes)
        while (m < nn) { FLUSH(); m++; }

        if (curg >= 0 && grp == 0) {
            atomicAdd(&poolL[curg * 64 + 4 * fl], p0);
            atomicAdd(&poolL[curg * 64 + 4 * fl + 1], p1);
            atomicAdd(&poolL[curg * 64 + 4 * fl + 2], p2);
            atomicAdd(&poolL[curg * 64 + 4 * fl + 3], p3);
        }
#undef AFF
#undef UNPK
#undef LDQ
#undef FLUSH
#undef CONSUME
    }

    if (threadIdx.x < 128) sred[threadIdx.x] = 0.f;
    __syncthreads();
    atomicAdd(&sred[lane], ls);
    atomicAdd(&sred[64 + lane], lss);
    __syncthreads();
    if (threadIdx.x < 128) atomicAdd(&stats1[threadIdx.x], sred[threadIdx.x]);
}

// ---------------- k_g2m: MFMA BN1+ReLU+GEMM2+BN2stats (unchanged) ----------------

__global__ __launch_bounds__(256) void k_g2m(
    const ushort_t* __restrict__ yb, const float* __restrict__ stats1,
    const float* __restrict__ g1, const float* __restrict__ b1,
    const float* __restrict__ W2, ushort_t* __restrict__ zb,
    float* __restrict__ stats2)
{
    __shared__ ushort_t zt[4][16][64];
    __shared__ float sred[128];
    int lane = threadIdx.x & 63;
    int wslot = threadIdx.x >> 6;
    int w = blockIdx.x * 4 + wslot;
    int r = lane & 15;
    int g = lane >> 4;

    if (threadIdx.x < 128) sred[threadIdx.x] = 0.f;
    __syncthreads();

    if (w < NN / 16) {
        int n0 = w * 16;

        float scL[8], shL[8], scH[8], shH[8];
#pragma unroll
        for (int e = 0; e < 8; e++) {
            int f = g * 8 + e;
            float mean = stats1[f] * (1.f / NN);
            float var  = stats1[64 + f] * (1.f / NN) - mean * mean;
            scL[e] = rsqrtf(var + BN_EPS) * g1[f];
            shL[e] = b1[f] - mean * scL[e];
            int f2 = 32 + f;
            float mean2 = stats1[f2] * (1.f / NN);
            float var2  = stats1[64 + f2] * (1.f / NN) - mean2 * mean2;
            scH[e] = rsqrtf(var2 + BN_EPS) * g1[f2];
            shH[e] = b1[f2] - mean2 * scH[e];
        }

        bf16x8 B00, B01, B02, B03, B10, B11, B12, B13;
#pragma unroll
        for (int j = 0; j < 8; j++) {
            int k0 = (g * 8 + j) * 64;
            int k1 = (32 + g * 8 + j) * 64;
            B00[j] = (short)f2bf(W2[k0 + r]);
            B01[j] = (short)f2bf(W2[k0 + 16 + r]);
            B02[j] = (short)f2bf(W2[k0 + 32 + r]);
            B03[j] = (short)f2bf(W2[k0 + 48 + r]);
            B10[j] = (short)f2bf(W2[k1 + r]);
            B11[j] = (short)f2bf(W2[k1 + 16 + r]);
            B12[j] = (short)f2bf(W2[k1 + 32 + r]);
            B13[j] = (short)f2bf(W2[k1 + 48 + r]);
        }

        union { uint4 u; ushort_t s[8]; } a0u, a1u;
        a0u.u = *(const uint4*)(yb + (size_t)(n0 + r) * 64 + g * 8);
        a1u.u = *(const uint4*)(yb + (size_t)(n0 + r) * 64 + 32 + g * 8);
        bf16x8 A0, A1;
#pragma unroll
        for (int e = 0; e < 8; e++) {
            float v0 = fmaxf(fmaf(bf2f(a0u.s[e]), scL[e], shL[e]), 0.f);
            float v1 = fmaxf(fmaf(bf2f(a1u.s[e]), scH[e], shH[e]), 0.f);
            A0[e] = (short)f2bf(v0);
            A1[e] = (short)f2bf(v1);
        }

        f32x4 acc0 = {0.f, 0.f, 0.f, 0.f};
        f32x4 acc1 = acc0, acc2 = acc0, acc3 = acc0;
        acc0 = __builtin_amdgcn_mfma_f32_16x16x32_bf16(A0, B00, acc0, 0, 0, 0);
        acc1 = __builtin_amdgcn_mfma_f32_16x16x32_bf16(A0, B01, acc1, 0, 0, 0);
        acc2 = __builtin_amdgcn_mfma_f32_16x16x32_bf16(A0, B02, acc2, 0, 0, 0);
        acc3 = __builtin_amdgcn_mfma_f32_16x16x32_bf16(A0, B03, acc3, 0, 0, 0);
        acc0 = __builtin_amdgcn_mfma_f32_16x16x32_bf16(A1, B10, acc0, 0, 0, 0);
        acc1 = __builtin_amdgcn_mfma_f32_16x16x32_bf16(A1, B11, acc1, 0, 0, 0);
        acc2 = __builtin_amdgcn_mfma_f32_16x16x32_bf16(A1, B12, acc2, 0, 0, 0);
        acc3 = __builtin_amdgcn_mfma_f32_16x16x32_bf16(A1, B13, acc3, 0, 0, 0);

        float ls0 = acc0.x + acc0.y + acc0.z + acc0.w;
        float ls1 = acc1.x + acc1.y + acc1.z + acc1.w;
        float ls2 = acc2.x + acc2.y + acc2.z + acc2.w;
        float ls3 = acc3.x + acc3.y + acc3.z + acc3.w;
        float lq0 = acc0.x * acc0.x + acc0.y * acc0.y + acc0.z * acc0.z + acc0.w * acc0.w;
        float lq1 = acc1.x * acc1.x + acc1.y * acc1.y + acc1.z * acc1.z + acc1.w * acc1.w;
        float lq2 = acc2.x * acc2.x + acc2.y * acc2.y + acc2.z * acc2.z + acc2.w * acc2.w;
        float lq3 = acc3.x * acc3.x + acc3.y * acc3.y + acc3.z * acc3.z + acc3.w * acc3.w;
        ls0 += __shfl_xor(ls0, 16); ls0 += __shfl_xor(ls0, 32);
        ls1 += __shfl_xor(ls1, 16); ls1 += __shfl_xor(ls1, 32);
        ls2 += __shfl_xor(ls2, 16); ls2 += __shfl_xor(ls2, 32);
        ls3 += __shfl_xor(ls3, 16); ls3 += __shfl_xor(ls3, 32);
        lq0 += __shfl_xor(lq0, 16); lq0 += __shfl_xor(lq0, 32);
        lq1 += __shfl_xor(lq1, 16); lq1 += __shfl_xor(lq1, 32);
        lq2 += __shfl_xor(lq2, 16); lq2 += __shfl_xor(lq2, 32);
        lq3 += __shfl_xor(lq3, 16); lq3 += __shfl_xor(lq3, 32);
        if (lane < 16) {
            atomicAdd(&sred[lane], ls0);
            atomicAdd(&sred[16 + lane], ls1);
            atomicAdd(&sred[32 + lane], ls2);
            atomicAdd(&sred[48 + lane], ls3);
            atomicAdd(&sred[64 + lane], lq0);
            atomicAdd(&sred[80 + lane], lq1);
            atomicAdd(&sred[96 + lane], lq2);
            atomicAdd(&sred[112 + lane], lq3);
        }

        zt[wslot][g * 4 + 0][r]      = f2bf(acc0.x);
        zt[wslot][g * 4 + 1][r]      = f2bf(acc0.y);
        zt[wslot][g * 4 + 2][r]      = f2bf(acc0.z);
        zt[wslot][g * 4 + 3][r]      = f2bf(acc0.w);
        zt[wslot][g * 4 + 0][16 + r] = f2bf(acc1.x);
        zt[wslot][g * 4 + 1][16 + r] = f2bf(acc1.y);
        zt[wslot][g * 4 + 2][16 + r] = f2bf(acc1.z);
        zt[wslot][g * 4 + 3][16 + r] = f2bf(acc1.w);
        zt[wslot][g * 4 + 0][32 + r] = f2bf(acc2.x);
        zt[wslot][g * 4 + 1][32 + r] = f2bf(acc2.y);
        zt[wslot][g * 4 + 2][32 + r] = f2bf(acc2.z);
        zt[wslot][g * 4 + 3][32 + r] = f2bf(acc2.w);
        zt[wslot][g * 4 + 0][48 + r] = f2bf(acc3.x);
        zt[wslot][g * 4 + 1][48 + r] = f2bf(acc3.y);
        zt[wslot][g * 4 + 2][48 + r] = f2bf(acc3.z);
        zt[wslot][g * 4 + 3][48 + r] = f2bf(acc3.w);

        int nl = lane >> 2;
        int c0 = (lane & 3) * 16;
        uint4 q0 = *(const uint4*)&zt[wslot][nl][c0];
        uint4 q1 = *(const uint4*)&zt[wslot][nl][c0 + 8];
        *(uint4*)(zb + (size_t)(n0 + nl) * 64 + c0) = q0;
        *(uint4*)(zb + (size_t)(n0 + nl) * 64 + c0 + 8) = q1;
    }

    __syncthreads();
    if (threadIdx.x < 128) atomicAdd(&stats2[threadIdx.x], sred[threadIdx.x]);
}

// ---------------- final hidden rep pooling (h_4) ----------------

__global__ __launch_bounds__(256) void k_pool4(
    const ushort_t* __restrict__ zb,
    const float* __restrict__ stats2, const float* __restrict__ g2, const float* __restrict__ b2,
    const int* __restrict__ gid, float* __restrict__ pool)
{
    int lane = threadIdx.x & 63;
    int wslot = threadIdx.x >> 6;
    int wid = blockIdx.x * 4 + wslot;
    int nw = gridDim.x * 4;
    int chunk = (NN + nw - 1) / nw;
    int n0 = wid * chunk, n1 = min(NN, n0 + chunk);
    if (n0 >= n1) return;

    float mean = stats2[lane] * (1.f / NN);
    float var  = stats2[64 + lane] * (1.f / NN) - mean * mean;
    float sc = rsqrtf(var + BN_EPS) * g2[lane];
    float sh = b2[lane] - mean * sc;

    int curg = -1;
    float pacc = 0.f;
    for (int n = n0; n < n1; ++n) {
        float v = fmaxf(fmaf(bf2f(zb[(size_t)n * 64 + lane]), sc, sh), 0.f);
        int g = gid[n];
        if (g != curg) {
            if (curg >= 0) atomicAdd(&pool[curg * 64 + lane], pacc);
            curg = g; pacc = 0.f;
        }
        pacc += v;
    }
    if (curg >= 0) atomicAdd(&pool[curg * 64 + lane], pacc);
}

// ---------------- epilogue ----------------

__global__ __launch_bounds__(256) void k_final(
    const float* __restrict__ pooled, const float* __restrict__ pW,
    const float* __restrict__ pb, float* __restrict__ out)
{
    int t = blockIdx.x * blockDim.x + threadIdx.x;
    int g = t >> 4;
    int c = t & 15;
    if (g >= NG) return;
    float acc = 0.f;
#pragma unroll
    for (int i = 0; i < 5; i++) {
        const float* P = pooled + (size_t)i * NG * 64 + g * 64;
        const float* W = pW + i * 64 * 16;
        float a = 0.f;
#pragma unroll
        for (int k = 0; k < 64; k++) a += P[k] * W[k * 16 + c];
        acc += a + pb[i * 16 + c];
    }
    float m = acc;
    for (int o = 1; o < 16; o <<= 1) m = fmaxf(m, __shfl_xor(m, o, 16));
    float e = expf(acc - m);
    float s = e;
    for (int o = 1; o < 16; o <<= 1) s += __shfl_xor(s, o, 16);
    out[g * 16 + c] = acc - m - logf(s);
}

// ---------------- launch ----------------

extern "C" void kernel_launch(void* const* d_in, const int* in_sizes, int n_in,
                              void* d_out, int out_size, void* d_ws, size_t ws_size,
                              hipStream_t stream) {
    const float* feat = (const float*)d_in[0];
    const float* W1   = (const float*)d_in[1];
    const float* W2   = (const float*)d_in[2];
    const float* bn1g = (const float*)d_in[3];
    const float* bn1b = (const float*)d_in[4];
    const float* bn2g = (const float*)d_in[5];
    const float* bn2b = (const float*)d_in[6];
    const float* pW   = (const float*)d_in[7];
    const float* pb   = (const float*)d_in[8];
    const int* src = (const int*)d_in[9];
    const int* dst = (const int*)d_in[10];
    const int* gid = (const int*)d_in[11];
    float* out = (float*)d_out;

    char* ws = (char*)d_ws;
    size_t o = 0;
    auto alloc = [&](size_t bytes) {
        void* p = ws + o;
        o += (bytes + 255) & ~(size_t)255;
        return p;
    };
    ushort_t* zb  = (ushort_t*)alloc((size_t)NN * 64 * 2);
    ushort_t* yb  = (ushort_t*)alloc((size_t)NN * 64 * 2);
    float* pooled = (float*)alloc((size_t)5 * NG * 64 * 4);
    float* stats  = (float*)alloc(1024 * 4);
    int* off  = (int*)alloc((size_t)(NN + 1) * 4);
    int* csr  = (int*)alloc((size_t)NE * 4);
    uint_t* binned = (uint_t*)alloc((size_t)NE * 4);
    int* cmat = (int*)alloc((size_t)BB * NBUK * 4);
    int* wmat = (int*)alloc((size_t)BB * NBUK * 4);
    int* bcnt = (int*)alloc(NBUK * 4);
    int* boff = (int*)alloc((NBUK + 1) * 4);
    int* wstart = (int*)alloc((NWAVES + 1) * 4);

    k_init<<<256, 256, 0, stream>>>(pooled, stats, bcnt);
    k_f2bf<<<1024, 256, 0, stream>>>((const float4*)feat, (uint2*)zb);
    k_cnt<<<BB, 256, 0, stream>>>(dst, cmat, bcnt);
    k_boffscan<<<NBUK, 256, 0, stream>>>(bcnt, cmat, wmat, boff);
    k_bin2<<<BB, 256, 0, stream>>>(src, dst, wmat, binned);
    k_bucket_finish<<<NBUK, 256, 0, stream>>>(binned, boff, off, csr);
    k_wstart<<<(NWAVES + 1 + 255) / 256, 256, 0, stream>>>(off, wstart);

    int g2m_blocks = (NN / 16 + 3) / 4;   // 1563
    for (int L = 0; L < 4; ++L) {
        float* s1 = stats + L * 256;
        float* s2 = s1 + 128;
        if (L == 0) {
            k_agg<0><<<AGG_BLOCKS, 256, 0, stream>>>(zb, nullptr, nullptr, nullptr,
                                                     csr, off, wstart, W1 + L * 4096, yb, s1,
                                                     gid, pooled + (size_t)L * NG * 64);
        } else {
            k_agg<1><<<AGG_BLOCKS, 256, 0, stream>>>(zb, stats + (L - 1) * 256 + 128,
                                                     bn2g + (L - 1) * 64, bn2b + (L - 1) * 64,
                                                     csr, off, wstart, W1 + L * 4096, yb, s1,
                                                     gid, pooled + (size_t)L * NG * 64);
        }
        k_g2m<<<g2m_blocks, 256, 0, stream>>>(yb, s1, bn1g + L * 64, bn1b + L * 64,
                                              W2 + L * 4096, zb, s2);
    }
    k_pool4<<<AGG_BLOCKS, 256, 0, stream>>>(zb, stats + 3 * 256 + 128, bn2g + 3 * 64, bn2b + 3 * 64,
                                            gid, pooled + (size_t)4 * NG * 64);
    k_final<<<(NG * 16 + 255) / 256, 256, 0, stream>>>(pooled, pW, pb, out);
}